// Round 2
// baseline (543.139 us; speedup 1.0000x reference)
//
#include <hip/hip_runtime.h>

// ---------------- CSR build ----------------

__global__ void k_zero_int(int* __restrict__ p, int n) {
    int i = blockIdx.x * blockDim.x + threadIdx.x;
    if (i < n) p[i] = 0;
}

__global__ void k_count(const int* __restrict__ col, int* __restrict__ cnt, int E) {
    int e = blockIdx.x * blockDim.x + threadIdx.x;
    if (e < E) atomicAdd(&cnt[col[e]], 1);
}

__global__ void k_dinv(const int* __restrict__ cnt, float* __restrict__ dinv, int n) {
    int i = blockIdx.x * blockDim.x + threadIdx.x;
    if (i < n) dinv[i] = rsqrtf((float)(cnt[i] + 1));  // +1 self-loop; always > 0
}

// exclusive scan, stage A: per-256-block scan + block sums
__global__ void k_scanA(const int* __restrict__ cnt, int* __restrict__ indptr,
                        int* __restrict__ bsum, int n) {
    __shared__ int s[256];
    int i = blockIdx.x * 256 + threadIdx.x;
    int v = (i < n) ? cnt[i] : 0;
    s[threadIdx.x] = v;
    __syncthreads();
    for (int off = 1; off < 256; off <<= 1) {
        int t = (threadIdx.x >= off) ? s[threadIdx.x - off] : 0;
        __syncthreads();
        s[threadIdx.x] += t;
        __syncthreads();
    }
    if (i < n) indptr[i] = s[threadIdx.x] - v;  // exclusive within block
    if (threadIdx.x == 255) bsum[blockIdx.x] = s[255];
}

// stage B: single-block exclusive scan of block sums (nb <= 512)
__global__ void k_scanB(int* __restrict__ bsum, int nb) {
    __shared__ int s[512];
    int tid = threadIdx.x;
    int v = (tid < nb) ? bsum[tid] : 0;
    s[tid] = v;
    __syncthreads();
    for (int off = 1; off < 512; off <<= 1) {
        int t = (tid >= off) ? s[tid - off] : 0;
        __syncthreads();
        s[tid] += t;
        __syncthreads();
    }
    if (tid < nb) bsum[tid] = s[tid] - v;  // exclusive
}

// stage C: add block offsets; set indptr[n] = E
__global__ void k_scanC(int* __restrict__ indptr, const int* __restrict__ bsum, int n, int E) {
    int i = blockIdx.x * blockDim.x + threadIdx.x;
    if (i < n) indptr[i] += bsum[i >> 8];
    if (i == n) indptr[n] = E;
}

__global__ void k_fill(const int* __restrict__ row, const int* __restrict__ col,
                       const int* __restrict__ indptr, int* __restrict__ cursor,
                       const float* __restrict__ dinv,
                       int* __restrict__ srcidx, float* __restrict__ enorm, int E) {
    int e = blockIdx.x * blockDim.x + threadIdx.x;
    if (e >= E) return;
    int r = row[e], c = col[e];
    int pos = indptr[c] + atomicAdd(&cursor[c], 1);
    srcidx[pos] = r;
    enorm[pos] = dinv[r] * dinv[c];
}

// ---------------- feature pipeline ----------------

// H0 = concat(x[N,120], comm_emb[comm_ids][N,8]) -> [N,128]
__global__ void k_concat(const float* __restrict__ x, const int* __restrict__ cid,
                         const float* __restrict__ cemb, float* __restrict__ out, int n) {
    int idx = blockIdx.x * blockDim.x + threadIdx.x;
    if (idx >= n * 128) return;
    int i = idx >> 7, k = idx & 127;
    float v;
    if (k < 120) v = x[i * 120 + k];
    else         v = cemb[cid[i] * 8 + (k - 120)];
    out[idx] = v;
}

// Out[16-row tile][64-col slice] = A[.,128] @ W[128, wstride] slice.
// LDS: W slice 32KB + A tile (pad 129 -> conflict-free) 8.25KB.
__global__ __launch_bounds__(256) void k_gemm64(const float* __restrict__ A,
                                                const float* __restrict__ W,
                                                float* __restrict__ Out,
                                                int n, int wstride, int ostride) {
    __shared__ float Wl[128 * 64];
    __shared__ float Al[16 * 129];
    int tid = threadIdx.x;
    int colbase = blockIdx.y * 64;
    int rowbase = blockIdx.x * 16;

    // stage W slice: 8192 floats = 2048 float4
    for (int j = tid; j < 2048; j += 256) {
        int k  = j >> 4;
        int c4 = j & 15;
        ((float4*)Wl)[j] = *(const float4*)&W[k * wstride + colbase + c4 * 4];
    }
    // stage A tile: 2048 scalars (padded rows)
    for (int j = tid; j < 2048; j += 256) {
        int r = j >> 7, k = j & 127;
        int gr = rowbase + r;
        Al[r * 129 + k] = (gr < n) ? A[gr * 128 + k] : 0.f;
    }
    __syncthreads();

    int r = tid & 15, cg = tid >> 4;  // 16 rows x 16 col-groups of 4
    float acc0 = 0.f, acc1 = 0.f, acc2 = 0.f, acc3 = 0.f;
#pragma unroll 4
    for (int k = 0; k < 128; ++k) {
        float a = Al[r * 129 + k];
        const float* w = &Wl[k * 64 + cg * 4];
        acc0 += a * w[0]; acc1 += a * w[1]; acc2 += a * w[2]; acc3 += a * w[3];
    }
    int gr = rowbase + r;
    if (gr < n) {
        float* o = &Out[gr * ostride + colbase + cg * 4];
        o[0] = acc0; o[1] = acc1; o[2] = acc2; o[3] = acc3;
    }
}

// CSR aggregate: out[i,f] = sum_e norm_e * H[src_e, f] + dinv[i]^2 * H[i,f] + b[f]
template <int NC, bool RELU>
__global__ void k_agg(const float* __restrict__ H, const int* __restrict__ indptr,
                      const int* __restrict__ srcidx, const float* __restrict__ enorm,
                      const float* __restrict__ dinv, const float* __restrict__ bias,
                      float* __restrict__ Out, int n) {
    int i = blockIdx.x;
    int f = threadIdx.x;
    float di = dinv[i];
    float acc = di * di * H[i * NC + f];
    int e0 = indptr[i], e1 = indptr[i + 1];
#pragma unroll 4
    for (int e = e0; e < e1; ++e) {
        acc += enorm[e] * H[srcidx[e] * NC + f];
    }
    acc += bias[f];
    if (RELU) acc = fmaxf(acc, 0.f);
    Out[i * NC + f] = acc;
}

// ---------------- launch ----------------

extern "C" void kernel_launch(void* const* d_in, const int* in_sizes, int n_in,
                              void* d_out, int out_size, void* d_ws, size_t ws_size,
                              hipStream_t stream) {
    const float* x    = (const float*)d_in[0];
    const int*   eidx = (const int*)d_in[1];   // harness delivers integers as int32
    const int*   cid  = (const int*)d_in[2];
    const float* cemb = (const float*)d_in[3];
    const float* W1   = (const float*)d_in[4];
    const float* b1   = (const float*)d_in[5];
    const float* W2   = (const float*)d_in[6];
    const float* b2   = (const float*)d_in[7];
    float* out = (float*)d_out;

    int n = in_sizes[2];      // comm_ids: one per node
    int E = in_sizes[1] / 2;  // edge_index [2,E]
    const int* row = eidx;
    const int* col = eidx + E;

    char* ws = (char*)d_ws;
    auto alloc = [&](size_t bytes) {
        char* p = ws;
        ws += (bytes + 255) & ~(size_t)255;
        return p;
    };
    float* dinv   = (float*)alloc((size_t)n * 4);
    int*   cnt    = (int*)  alloc((size_t)n * 4);
    int*   indptr = (int*)  alloc((size_t)(n + 1) * 4);
    int*   bsum   = (int*)  alloc(4096);
    int*   srcidx = (int*)  alloc((size_t)E * 4);
    float* enorm  = (float*)alloc((size_t)E * 4);
    float* bufA   = (float*)alloc((size_t)n * 128 * 4);
    float* bufB   = (float*)alloc((size_t)n * 128 * 4);

    int nb = (n + 255) / 256;

    // CSR build
    k_zero_int<<<nb, 256, 0, stream>>>(cnt, n);
    k_count<<<(E + 255) / 256, 256, 0, stream>>>(col, cnt, E);
    k_dinv<<<nb, 256, 0, stream>>>(cnt, dinv, n);
    k_scanA<<<nb, 256, 0, stream>>>(cnt, indptr, bsum, n);
    k_scanB<<<1, 512, 0, stream>>>(bsum, nb);
    k_scanC<<<(n + 1 + 255) / 256, 256, 0, stream>>>(indptr, bsum, n, E);
    k_zero_int<<<nb, 256, 0, stream>>>(cnt, n);  // reuse as cursor
    k_fill<<<(E + 255) / 256, 256, 0, stream>>>(row, col, indptr, cnt, dinv, srcidx, enorm, E);

    // layer 1
    k_concat<<<((size_t)n * 128 + 255) / 256, 256, 0, stream>>>(x, cid, cemb, bufB, n);
    dim3 g1((n + 15) / 16, 2);
    k_gemm64<<<g1, 256, 0, stream>>>(bufB, W1, bufA, n, 128, 128);
    k_agg<128, true><<<n, 128, 0, stream>>>(bufA, indptr, srcidx, enorm, dinv, b1, bufB, n);

    // layer 2
    dim3 g2((n + 15) / 16, 1);
    k_gemm64<<<g2, 256, 0, stream>>>(bufB, W2, bufA, n, 64, 64);
    k_agg<64, false><<<n, 64, 0, stream>>>(bufA, indptr, srcidx, enorm, dinv, b2, out, n);
}